// Round 6
// baseline (490.314 us; speedup 1.0000x reference)
//
#include <hip/hip_runtime.h>
#include <hip/hip_bf16.h>
#include <math.h>

#define B_   2
#define S_   2048
#define HID_ 2048
#define NH_  16
#define HD_  128
#define QKV_ (3 * NH_ * HD_)   // 6144
#define EPS_ 1e-5f

typedef __bf16 bf16x8 __attribute__((ext_vector_type(8)));
typedef __bf16 bf16x4 __attribute__((ext_vector_type(4)));
typedef __bf16 bf16x2 __attribute__((ext_vector_type(2)));
typedef float  f32x4  __attribute__((ext_vector_type(4)));

// ---------------------------------------------------------------------------
// fp32 -> bf16 cast for all three inputs in ONE launch.
// ---------------------------------------------------------------------------
__global__ __launch_bounds__(256) void cast3_f32_bf16(
    const float* __restrict__ a, __bf16* __restrict__ ao, int na4,
    const float* __restrict__ b, __bf16* __restrict__ bo, int nb4,
    const float* __restrict__ c, __bf16* __restrict__ co, int nc4) {
    int j = blockIdx.x * 256 + threadIdx.x;
    const float* src;
    __bf16* dst;
    if (j < na4) {
        src = a; dst = ao;
    } else {
        j -= na4;
        if (j < nb4) {
            src = b; dst = bo;
        } else {
            j -= nb4;
            if (j >= nc4) return;
            src = c; dst = co;
        }
    }
    float4 v = reinterpret_cast<const float4*>(src)[j];
    bf16x4 o = {(__bf16)v.x, (__bf16)v.y, (__bf16)v.z, (__bf16)v.w};
    reinterpret_cast<bf16x4*>(dst)[j] = o;
}

__device__ __forceinline__ void gload_lds16(const __bf16* g, __bf16* l) {
    __builtin_amdgcn_global_load_lds(
        (const __attribute__((address_space(1))) void*)g,
        (__attribute__((address_space(3))) void*)l, 16, 0, 0);
}

#define BARR  __builtin_amdgcn_s_barrier()
#define LGKM0 asm volatile("s_waitcnt lgkmcnt(0)" ::: "memory")
#define FENCE asm volatile("" ::: "memory")

// ---------------------------------------------------------------------------
// 256x192-tile 8-phase bf16 MFMA GEMM (NT) — R5-proven, GEMM1.
// ---------------------------------------------------------------------------
__device__ __forceinline__ void read_a4x(const __bf16* bc, int wm, int lrow,
                                         int quad, int swz, int qq,
                                         bf16x8 (&af)[2][2]) {
#pragma unroll
    for (int i2 = 0; i2 < 2; ++i2)
#pragma unroll
        for (int kk = 0; kk < 2; ++kk)
            af[i2][kk] = *reinterpret_cast<const bf16x8*>(
                &bc[(wm * 128 + (qq * 2 + i2) * 16 + lrow) * 64 +
                    (((kk * 4 + quad) ^ swz) << 3)]);
}

__device__ __forceinline__ void read_b6(const __bf16* bc, int wn, int lrow,
                                        int quad, int swz,
                                        bf16x8 (&bf)[3][2]) {
#pragma unroll
    for (int j = 0; j < 3; ++j)
#pragma unroll
        for (int kk = 0; kk < 2; ++kk)
            bf[j][kk] = *reinterpret_cast<const bf16x8*>(
                &bc[16384 + (wn * 48 + j * 16 + lrow) * 64 +
                    (((kk * 4 + quad) ^ swz) << 3)]);
}

__device__ __forceinline__ void mfma12(int qq, const bf16x8 (&af)[2][2],
                                       const bf16x8 (&bf)[3][2],
                                       f32x4 (&acc)[8][3]) {
    __builtin_amdgcn_s_setprio(1);
#pragma unroll
    for (int i2 = 0; i2 < 2; ++i2)
#pragma unroll
        for (int j = 0; j < 3; ++j)
#pragma unroll
            for (int kk = 0; kk < 2; ++kk)
                acc[qq * 2 + i2][j] = __builtin_amdgcn_mfma_f32_16x16x32_bf16(
                    af[i2][kk], bf[j][kk], acc[qq * 2 + i2][j], 0, 0, 0);
    __builtin_amdgcn_s_setprio(0);
}

__global__ __launch_bounds__(512, 2) void gemm1_192(
    const __bf16* __restrict__ A, const __bf16* __restrict__ Bm,
    __bf16* __restrict__ C, int M, int N, int K) {
    __shared__ __bf16 lds[2][28672];   // [buf][A 256x64 | B 192x64] 112 KB

    const int tid  = threadIdx.x;
    const int w    = tid >> 6;         // 0..7
    const int lane = tid & 63;
    const int lrow = lane & 15;
    const int quad = lane >> 4;
    const int wm   = w >> 2;           // 0..1 (M half, 128 rows)
    const int wn   = w & 3;            // 0..3 (N quarter, 48 cols)
    const int swz  = lrow & 7;

    // bijective XCD swizzle (512 % 8 == 0)
    const int chunk = (int)gridDim.x >> 3;
    const int flat  = (int)blockIdx.x;
    const int vid   = (flat & 7) * chunk + (flat >> 3);
    const int m0 = (vid & 15) * 256;   // 16 m-tiles
    const int n0 = (vid >> 4) * 192;   // 32 n-tiles

    const int lr = lane >> 3;
    const int lg = lane & 7;
    const size_t K64 = (size_t)K * 64;
    const __bf16* pA = A  + (size_t)(m0 + w * 8 + lr) * K + ((lg ^ lr) << 3);
    const __bf16* pB = Bm + (size_t)(n0 + w * 8 + lr) * K + ((lg ^ lr) << 3);

#define STA(c, tt, dst) gload_lds16(pA + (size_t)(c) * K64 + (size_t)(tt) * 64, \
                                    (dst) + (c) * 4096 + w * 512)
#define STB(c, tt, dst) gload_lds16(pB + (size_t)(c) * K64 + (size_t)(tt) * 64, \
                                    (dst) + 16384 + (c) * 4096 + w * 512)

    f32x4 acc[8][3] = {};
    bf16x8 af[2][2], bf[3][2];

    {
        __bf16* d = &lds[0][0];
        STB(0, 0, d); STB(1, 0, d); STB(2, 0, d);
        FENCE;
        STA(0, 0, d); STA(2, 0, d);
        FENCE;
        STA(1, 0, d); STA(3, 0, d);
    }
    asm volatile("s_waitcnt vmcnt(2)" ::: "memory");
    BARR;

    const int nt = K >> 6;
    for (int t = 0; t < nt - 1; ++t) {
        __bf16* bc = &lds[t & 1][0];
        __bf16* bn = &lds[(t & 1) ^ 1][0];
        const int tn = t + 1;
        read_a4x(bc, wm, lrow, quad, swz, 0, af);
        read_b6(bc, wn, lrow, quad, swz, bf);
        STB(0, tn, bn); STB(1, tn, bn);
        BARR; LGKM0;
        mfma12(0, af, bf, acc);
        BARR;
        read_a4x(bc, wm, lrow, quad, swz, 1, af);
        STB(2, tn, bn);
        BARR; LGKM0;
        mfma12(1, af, bf, acc);
        asm volatile("s_waitcnt vmcnt(3)" ::: "memory");
        BARR;
        read_a4x(bc, wm, lrow, quad, swz, 2, af);
        STA(0, tn, bn); STA(2, tn, bn);
        BARR; LGKM0;
        mfma12(2, af, bf, acc);
        BARR;
        read_a4x(bc, wm, lrow, quad, swz, 3, af);
        STA(1, tn, bn); STA(3, tn, bn);
        BARR; LGKM0;
        mfma12(3, af, bf, acc);
        asm volatile("s_waitcnt vmcnt(2)" ::: "memory");
        BARR;
    }
    {
        __bf16* bc = &lds[(nt - 1) & 1][0];
        read_a4x(bc, wm, lrow, quad, swz, 0, af);
        read_b6(bc, wn, lrow, quad, swz, bf);
        BARR; LGKM0;
        mfma12(0, af, bf, acc);
        BARR;
        read_a4x(bc, wm, lrow, quad, swz, 1, af);
        BARR; LGKM0;
        mfma12(1, af, bf, acc);
        asm volatile("s_waitcnt vmcnt(0)" ::: "memory");
        BARR;
        read_a4x(bc, wm, lrow, quad, swz, 2, af);
        BARR; LGKM0;
        mfma12(2, af, bf, acc);
        BARR;
        read_a4x(bc, wm, lrow, quad, swz, 3, af);
        BARR; LGKM0;
        mfma12(3, af, bf, acc);
    }
#undef STA
#undef STB

#pragma unroll
    for (int mf = 0; mf < 8; ++mf) {
#pragma unroll
        for (int r = 0; r < 4; ++r) {
            int row = m0 + wm * 128 + mf * 16 + quad * 4 + r;
            size_t cb = (size_t)row * N + n0 + wn * 48 + lrow;
#pragma unroll
            for (int j = 0; j < 3; ++j)
                C[cb + j * 16] = (__bf16)acc[mf][j][r];
        }
    }
}

// ---------------------------------------------------------------------------
// 128x256-tile ring-3 bf16 MFMA GEMM (NT) — R2-proven kernel, GEMM2.
// ---------------------------------------------------------------------------
__device__ __forceinline__ void stage_tile6(
    const __bf16* pA, const __bf16* pB, __bf16* buf, int w, int K) {
#pragma unroll
    for (int s = 0; s < 2; ++s)
        gload_lds16(pA + (size_t)s * 64 * K, buf + s * 4096 + w * 512);
#pragma unroll
    for (int s = 0; s < 4; ++s)
        gload_lds16(pB + (size_t)s * 64 * K, buf + 8192 + s * 4096 + w * 512);
}

template <typename OutT>
__global__ __launch_bounds__(512, 2) void gemm_bt_8ph(
    const __bf16* __restrict__ A, const __bf16* __restrict__ Bm,
    OutT* __restrict__ C, int M, int N, int K) {
    __shared__ __bf16 lds[3][24576];   // [buf][ A:128x64 | B:256x64 ] 144 KB

    const int tid  = threadIdx.x;
    const int w    = tid >> 6;         // 0..7
    const int lane = tid & 63;
    const int lrow = lane & 15;
    const int quad = lane >> 4;
    const int wm   = w >> 2;           // 0..1  (M half)
    const int wn   = w & 3;            // 0..3  (N quarter)

    const int chunk = (int)gridDim.x >> 3;
    const int flat  = (int)blockIdx.x;
    const int vid   = (flat & 7) * chunk + (flat >> 3);
    const int by    = vid & 31;        // M/128 = 32
    const int bx    = vid >> 5;
    const int m0 = by * 128;
    const int n0 = bx * 256;

    const int lr = lane >> 3;
    const int lg = lane & 7;
    const __bf16* pA = A  + (size_t)(m0 + w * 8 + lr) * K + ((lg ^ lr) << 3);
    const __bf16* pB = Bm + (size_t)(n0 + w * 8 + lr) * K + ((lg ^ lr) << 3);

    const int nt = K >> 6;             // K-tiles of 64
    f32x4 acc[4][4] = {};

    stage_tile6(pA, pB, &lds[0][0], w, K);
    stage_tile6(pA + 64, pB + 64, &lds[1][0], w, K);

    int cur = 0;
    for (int t = 0; t < nt; ++t) {
        __bf16* bufc = &lds[cur][0];
        int nxt = cur + 2; if (nxt >= 3) nxt -= 3;
        if (t + 2 < nt) {
            stage_tile6(pA + (size_t)(t + 2) * 64, pB + (size_t)(t + 2) * 64,
                        &lds[nxt][0], w, K);
            asm volatile("s_waitcnt vmcnt(12)" ::: "memory");
        } else if (t + 1 < nt) {
            asm volatile("s_waitcnt vmcnt(6)" ::: "memory");
        } else {
            asm volatile("s_waitcnt vmcnt(0)" ::: "memory");
        }
        BARR;
        FENCE;

#pragma unroll
        for (int q = 0; q < 2; ++q) {          // 2 phases x 16 MFMA per K-tile
            bf16x8 af[2][2], bfv[4][2];
#pragma unroll
            for (int i = 0; i < 2; ++i)
#pragma unroll
                for (int kk = 0; kk < 2; ++kk)
                    af[i][kk] = *reinterpret_cast<const bf16x8*>(
                        &bufc[(wm * 64 + (q * 2 + i) * 16 + lrow) * 64 +
                              (((kk * 4 + quad) ^ (lrow & 7)) << 3)]);
#pragma unroll
            for (int j = 0; j < 4; ++j)
#pragma unroll
                for (int kk = 0; kk < 2; ++kk)
                    bfv[j][kk] = *reinterpret_cast<const bf16x8*>(
                        &bufc[8192 + (wn * 64 + j * 16 + lrow) * 64 +
                              (((kk * 4 + quad) ^ (lrow & 7)) << 3)]);
            BARR;
            FENCE;
            __builtin_amdgcn_s_setprio(1);
#pragma unroll
            for (int i = 0; i < 2; ++i)
#pragma unroll
                for (int j = 0; j < 4; ++j)
#pragma unroll
                    for (int kk = 0; kk < 2; ++kk)
                        acc[q * 2 + i][j] =
                            __builtin_amdgcn_mfma_f32_16x16x32_bf16(
                                af[i][kk], bfv[j][kk], acc[q * 2 + i][j],
                                0, 0, 0);
            __builtin_amdgcn_s_setprio(0);
        }
        BARR;
        FENCE;
        cur = (cur == 2) ? 0 : cur + 1;
    }

#pragma unroll
    for (int mi = 0; mi < 4; ++mi) {
#pragma unroll
        for (int r = 0; r < 4; ++r) {
            int row = m0 + wm * 64 + mi * 16 + quad * 4 + r;
            size_t basec = (size_t)row * N + n0 + wn * 64 + lrow;
#pragma unroll
            for (int nj = 0; nj < 4; ++nj)
                C[basec + nj * 16] = (OutT)acc[mi][nj][r];
        }
    }
}

// ---------------------------------------------------------------------------
// RMSNorm (flat 2048) + RoPE in place on bf16 q or k.  (unchanged)
// ---------------------------------------------------------------------------
__global__ __launch_bounds__(256) void normrope_kernel(
    __bf16* __restrict__ qkv, const float* __restrict__ qw,
    const float* __restrict__ kw) {
    const int row = blockIdx.x;
    const int sel = blockIdx.y;
    const int pos = row & (S_ - 1);
    __bf16* p = qkv + (size_t)row * QKV_ + sel * 2048;
    const float* w = sel ? kw : qw;

    __shared__ float buf[2048];
    __shared__ float red[4];
    const int tid = threadIdx.x;
    const int e   = tid * 8;

    bf16x8 t = *reinterpret_cast<const bf16x8*>(&p[e]);
    float xs[8];
    float ss = 0.f;
#pragma unroll
    for (int u = 0; u < 8; ++u) {
        xs[u] = (float)t[u];
        buf[e + u] = xs[u];
        ss += xs[u] * xs[u];
    }
#pragma unroll
    for (int off = 32; off > 0; off >>= 1) ss += __shfl_xor(ss, off, 64);
    if ((tid & 63) == 0) red[tid >> 6] = ss;
    __syncthreads();
    float total = red[0] + red[1] + red[2] + red[3];
    float scale = rsqrtf(total * (1.f / 2048.f) + EPS_);

    const float kfreq2 = -0.20762050593046f;  // -log2(10000)/64
    const int jbase = e & 63;
    const bool first = (e & 127) < 64;
    const int ep = e ^ 64;

    float ps[8], ws[8], pw[8];
#pragma unroll
    for (int u = 0; u < 8; ++u) ps[u] = buf[ep + u];
    float4 w0 = *reinterpret_cast<const float4*>(&w[e]);
    float4 w1 = *reinterpret_cast<const float4*>(&w[e + 4]);
    float4 p0 = *reinterpret_cast<const float4*>(&w[ep]);
    float4 p1 = *reinterpret_cast<const float4*>(&w[ep + 4]);
    ws[0]=w0.x; ws[1]=w0.y; ws[2]=w0.z; ws[3]=w0.w;
    ws[4]=w1.x; ws[5]=w1.y; ws[6]=w1.z; ws[7]=w1.w;
    pw[0]=p0.x; pw[1]=p0.y; pw[2]=p0.z; pw[3]=p0.w;
    pw[4]=p1.x; pw[5]=p1.y; pw[6]=p1.z; pw[7]=p1.w;

    bf16x8 o8;
#pragma unroll
    for (int u = 0; u < 8; ++u) {
        float inv_freq = exp2f((float)(jbase + u) * kfreq2);
        float ang = (float)pos * inv_freq;
        float sn = __sinf(ang);
        float cs = __cosf(ang);
        float a  = xs[u] * scale * ws[u];
        float bb = ps[u] * scale * pw[u];
        float o  = first ? (a * cs - bb * sn) : (a * cs + bb * sn);
        o8[u] = (__bf16)o;
    }
    *reinterpret_cast<bf16x8*>(&p[e]) = o8;
}

// ---------------------------------------------------------------------------
// MFMA flash attention — R6: paired complementary q-tiles per block
// (qtH=8+p, qtL=7-p; every block = exactly 68 compute-iterations -> uniform
// load, grid 256 = 1 block/CU deterministic), K/V stream shared by both
// tiles (staging per unit compute halves), and Ks XOR-swizzle
// (granule ^= (row>>1)&3, applied on the gload_lds GLOBAL source + same XOR
// on ds_read) to kill the 8-way K-fragment bank conflict (4.26M/dispatch).
// Per-wave structure (16-row strip, S^T trick, static-max softmax,
// prefetch-1 ping-pong) unchanged from the proven kernel.
// ---------------------------------------------------------------------------
#define VTP 36   // Vt/Pb row stride in bf16: 72B rows, 2-way-max aliasing

__device__ __forceinline__ void attn_tile_step(
    const __bf16* KsB, const __bf16* VtB, __bf16* PbW,
    int kt, int ktw, int lrow, int quad, int kgq,
    const bf16x8 (&qf)[4], int qrow, f32x4 (&o)[8], float& lp) {
    if (kt > ktw) return;
    const float sl2 = 0.12751743671f;   // (1/sqrt(128))*log2(e)
    f32x4 sc[2] = {};
    __builtin_amdgcn_s_setprio(1);
#pragma unroll
    for (int kc = 0; kc < 4; ++kc) {
        bf16x8 kf0 = *reinterpret_cast<const bf16x8*>(
            &KsB[kc * 1024 + lrow * 32 + kgq]);
        bf16x8 kf1 = *reinterpret_cast<const bf16x8*>(
            &KsB[kc * 1024 + (16 + lrow) * 32 + kgq]);
        sc[0] = __builtin_amdgcn_mfma_f32_16x16x32_bf16(
            kf0, qf[kc], sc[0], 0, 0, 0);
        sc[1] = __builtin_amdgcn_mfma_f32_16x16x32_bf16(
            kf1, qf[kc], sc[1], 0, 0, 0);
    }
    __builtin_amdgcn_s_setprio(0);
    const bool diag = (kt == ktw);
    float p[2][4];
#pragma unroll
    for (int m2 = 0; m2 < 2; ++m2)
#pragma unroll
        for (int r = 0; r < 4; ++r) {
            float s = sc[m2][r] * sl2 - 32.f;
            if (diag && kt * 32 + m2 * 16 + quad * 4 + r > qrow)
                s = -1e30f;
            p[m2][r] = exp2f(s);
            lp += p[m2][r];
        }
#pragma unroll
    for (int m2 = 0; m2 < 2; ++m2) {
        bf16x4 pb = {(__bf16)p[m2][0], (__bf16)p[m2][1],
                     (__bf16)p[m2][2], (__bf16)p[m2][3]};
        *reinterpret_cast<bf16x4*>(&PbW[lrow * VTP + m2 * 16 + quad * 4]) = pb;
    }
    bf16x8 pf = *reinterpret_cast<const bf16x8*>(&PbW[lrow * VTP + quad * 8]);
    __builtin_amdgcn_s_setprio(1);
#pragma unroll
    for (int dt = 0; dt < 8; ++dt) {
        bf16x8 vf = *reinterpret_cast<const bf16x8*>(
            &VtB[(dt * 16 + lrow) * VTP + quad * 8]);
        o[dt] = __builtin_amdgcn_mfma_f32_16x16x32_bf16(
            vf, pf, o[dt], 0, 0, 0);
    }
    __builtin_amdgcn_s_setprio(0);
}

__global__ __launch_bounds__(512, 2) void attn_mfma(
    const __bf16* __restrict__ qkv, __bf16* __restrict__ aout) {
    // 256 blocks = 32 bh x 8 pairs; XCD swizzle (256 % 8 == 0):
    // XCD c gets vid in [c*32, c*32+32) = bh in [c*4, c*4+4) (4 MB K/V = L2).
    const int flat = (int)blockIdx.x;
    const int vid  = (flat & 7) * 32 + (flat >> 3);
    const int bh   = vid >> 3;
    const int pr   = vid & 7;
    const int qtH  = 8 + pr;              // heavy q-tile
    const int qtL  = 7 - pr;              // light q-tile (qtH + qtL = 15)
    const int b    = bh >> 4;
    const int h    = bh & (NH_ - 1);
    const int tid  = threadIdx.x;
    const int w    = tid >> 6;            // 0..7
    const int lane = tid & 63;
    const int lrow = lane & 15;
    const int quad = lane >> 4;

    __shared__ __bf16 Ks[2][4][32 * 32];   // [buf][kc][key*32+c]  16 KB
    __shared__ __bf16 Vt[2][128 * VTP];    // [buf][d*VTP+key]     18 KB
    __shared__ __bf16 Pb[8][16 * VTP];     // [wave][q*VTP+key]     9 KB

    const size_t base = (size_t)(b * S_) * QKV_ + (size_t)h * HD_;
    const int qrowH = qtH * 128 + w * 16 + lrow;
    const int qrowL = qtL * 128 + w * 16 + lrow;

    // resident Q B-frags for both tiles
    bf16x8 qfH[4], qfL[4];
#pragma unroll
    for (int kc = 0; kc < 4; ++kc) {
        qfH[kc] = *reinterpret_cast<const bf16x8*>(
            &qkv[base + (size_t)qrowH * QKV_ + kc * 32 + quad * 8]);
        qfL[kc] = *reinterpret_cast<const bf16x8*>(
            &qkv[base + (size_t)qrowL * QKV_ + kc * 32 + quad * 8]);
    }

    f32x4 oH[8] = {}, oL[8] = {};
    float lpH = 0.f, lpL = 0.f;

    const int ktmaxH_w  = 4 * qtH + (w >> 1);
    const int ktmaxL_w  = 4 * qtL + (w >> 1);
    const int ktmax_blk = 4 * qtH + 3;
    const int kgq = (quad ^ ((lrow >> 1) & 3)) * 8;  // swizzled K granule

    // K staging: wave w stages chunk (w>>1), key-half (w&1), one gload.
    // Global col granule pre-swizzled: (lane&3) ^ ((lane>>3)&3) == read XOR
    // key for LDS row (w&1)*16 + (lane>>2)  (dest stays linear, rule 21).
    const __bf16* kg0 = qkv + base + 2048 +
                        (size_t)((w & 1) * 16 + (lane >> 2)) * QKV_ +
                        (w >> 1) * 32 + (((lane & 3) ^ ((lane >> 3) & 3)) << 3);
    // V staging: waves 0-3 (256 threads), g = tid>>4 (d-group), kp key pair.
    const int g  = tid >> 4;
    const int kp = tid & 15;
    const __bf16* vg0 = qkv + base + 4096 + (size_t)(kp * 2) * QKV_ + g * 8;

    // ---- preload tile 0: K direct-to-LDS buf0, V into regs ----
    gload_lds16(kg0, &Ks[0][w >> 1][(w & 1) * 512]);
    bf16x8 v0 = {}, v1 = {};
    if (tid < 256) {
        v0 = *reinterpret_cast<const bf16x8*>(vg0);
        v1 = *reinterpret_cast<const bf16x8*>(vg0 + QKV_);
    }

    for (int kt = 0; kt <= ktmax_blk; ++kt) {
        const int buf = kt & 1;
        // 1. V regs (tile kt) -> Vt[buf]
        if (tid < 256) {
#pragma unroll
            for (int u = 0; u < 8; ++u) {
                bf16x2 pr2 = {v0[u], v1[u]};
                *reinterpret_cast<bf16x2*>(
                    &Vt[buf][(g * 8 + u) * VTP + kp * 2]) = pr2;
            }
        }
        // 2. barrier: Ks[buf]/Vt[buf] ready for all waves
        __syncthreads();
        // 3. prefetch tile kt+1 into the other buffer / regs
        if (kt < ktmax_blk) {
            const __bf16* kg = kg0 + (size_t)(kt + 1) * 32 * QKV_;
            gload_lds16(kg, &Ks[buf ^ 1][w >> 1][(w & 1) * 512]);
            if (tid < 256) {
                const __bf16* vg = vg0 + (size_t)(kt + 1) * 32 * QKV_;
                v0 = *reinterpret_cast<const bf16x8*>(vg);
                v1 = *reinterpret_cast<const bf16x8*>(vg + QKV_);
            }
        }
        // 4. compute both tiles on buf (shared K/V stream)
        attn_tile_step(&Ks[buf][0][0], &Vt[buf][0], &Pb[w][0],
                       kt, ktmaxH_w, lrow, quad, kgq, qfH, qrowH, oH, lpH);
        attn_tile_step(&Ks[buf][0][0], &Vt[buf][0], &Pb[w][0],
                       kt, ktmaxL_w, lrow, quad, kgq, qfL, qrowL, oL, lpL);
    }

    // epilogue: per-tile l-reduction across quad groups, scale, store
#pragma unroll
    for (int sel = 0; sel < 2; ++sel) {
        f32x4* o = sel ? oL : oH;
        float lp = sel ? lpL : lpH;
        const int qrow = sel ? qrowL : qrowH;
        lp += __shfl_xor(lp, 16, 64);
        lp += __shfl_xor(lp, 32, 64);
        const float invl = 1.f / lp;
        const size_t orow =
            (size_t)(b * S_ + qrow) * (NH_ * HD_) + (size_t)h * HD_;
#pragma unroll
        for (int dt = 0; dt < 8; ++dt) {
            bf16x4 ov = {(__bf16)(o[dt][0] * invl), (__bf16)(o[dt][1] * invl),
                         (__bf16)(o[dt][2] * invl), (__bf16)(o[dt][3] * invl)};
            *reinterpret_cast<bf16x4*>(&aout[orow + dt * 16 + quad * 4]) = ov;
        }
    }
}

// ---------------------------------------------------------------------------
extern "C" void kernel_launch(void* const* d_in, const int* in_sizes, int n_in,
                              void* d_out, int out_size, void* d_ws,
                              size_t ws_size, hipStream_t stream) {
    const float* x     = (const float*)d_in[0];
    const float* w_in  = (const float*)d_in[1];
    const float* w_out = (const float*)d_in[2];
    const float* qw    = (const float*)d_in[3];
    const float* kw    = (const float*)d_in[4];
    float* out = (float*)d_out;

    const int M = B_ * S_;  // 4096
    // workspace (bytes), peak 96 MiB:
    //   [0,48M) qkv_bf16 | [48M,56M) w_out_bf16 | [56M,72M) x_bf16/attn_bf16
    //   [72M,96M) w_in_bf16
    char* ws = (char*)d_ws;
    __bf16* qkv_b   = (__bf16*)(ws);
    __bf16* w_out_b = (__bf16*)(ws + (size_t)50331648);
    __bf16* x_b     = (__bf16*)(ws + (size_t)58720256);
    __bf16* attn_b  = x_b;  // x_bf16 dead after GEMM1
    __bf16* w_in_b  = (__bf16*)(ws + (size_t)75497472);

    dim3 blk(256);

    // single fused cast launch: x, w_in, w_out
    {
        const int na4 = (M * HID_) / 4;          // 2,097,152
        const int nb4 = (QKV_ * HID_) / 4;       // 3,145,728
        const int nc4 = (HID_ * NH_ * HD_) / 4;  // 1,048,576
        const int tot = na4 + nb4 + nc4;
        cast3_f32_bf16<<<dim3((tot + 255) / 256), blk, 0, stream>>>(
            x, x_b, na4, w_in, w_in_b, nb4, w_out, w_out_b, nc4);
    }

    // qkv = x @ w_in^T   (4096 x 6144 x 2048): 16x32 = 512 blocks = 2 rounds
    gemm1_192<<<dim3((M / 256) * (QKV_ / 192)), dim3(512), 0, stream>>>(
        x_b, w_in_b, qkv_b, M, QKV_, HID_);
    // rmsnorm + rope on q and k, in place
    normrope_kernel<<<dim3(M, 2), blk, 0, stream>>>(qkv_b, qw, kw);
    // causal MFMA flash attention: paired q-tiles, 256 blocks = 1/CU
    attn_mfma<<<dim3(256), dim3(512), 0, stream>>>(qkv_b, attn_b);
    // out = attn @ w_out^T  (4096 x 2048 x 2048): 32x8 = 256 blocks = 1 round
    gemm_bt_8ph<float><<<dim3((M / 128) * (HID_ / 256)), dim3(512), 0,
                         stream>>>(attn_b, w_out_b, out, M, HID_, NH_ * HD_);
}

// Round 7
// 383.596 us; speedup vs baseline: 1.2782x; 1.2782x over previous
//
#include <hip/hip_runtime.h>
#include <hip/hip_bf16.h>
#include <math.h>

#define B_   2
#define S_   2048
#define HID_ 2048
#define NH_  16
#define HD_  128
#define QKV_ (3 * NH_ * HD_)   // 6144
#define EPS_ 1e-5f

typedef __bf16 bf16x8 __attribute__((ext_vector_type(8)));
typedef __bf16 bf16x4 __attribute__((ext_vector_type(4)));
typedef __bf16 bf16x2 __attribute__((ext_vector_type(2)));
typedef float  f32x4  __attribute__((ext_vector_type(4)));

// ---------------------------------------------------------------------------
// fp32 -> bf16 cast for all three inputs in ONE launch.
// ---------------------------------------------------------------------------
__global__ __launch_bounds__(256) void cast3_f32_bf16(
    const float* __restrict__ a, __bf16* __restrict__ ao, int na4,
    const float* __restrict__ b, __bf16* __restrict__ bo, int nb4,
    const float* __restrict__ c, __bf16* __restrict__ co, int nc4) {
    int j = blockIdx.x * 256 + threadIdx.x;
    const float* src;
    __bf16* dst;
    if (j < na4) {
        src = a; dst = ao;
    } else {
        j -= na4;
        if (j < nb4) {
            src = b; dst = bo;
        } else {
            j -= nb4;
            if (j >= nc4) return;
            src = c; dst = co;
        }
    }
    float4 v = reinterpret_cast<const float4*>(src)[j];
    bf16x4 o = {(__bf16)v.x, (__bf16)v.y, (__bf16)v.z, (__bf16)v.w};
    reinterpret_cast<bf16x4*>(dst)[j] = o;
}

__device__ __forceinline__ void gload_lds16(const __bf16* g, __bf16* l) {
    __builtin_amdgcn_global_load_lds(
        (const __attribute__((address_space(1))) void*)g,
        (__attribute__((address_space(3))) void*)l, 16, 0, 0);
}

#define BARR  __builtin_amdgcn_s_barrier()
#define LGKM0 asm volatile("s_waitcnt lgkmcnt(0)" ::: "memory")
#define FENCE asm volatile("" ::: "memory")

// ---------------------------------------------------------------------------
// 256x192-tile 8-phase bf16 MFMA GEMM (NT) — R5-proven, GEMM1.
// ---------------------------------------------------------------------------
__device__ __forceinline__ void read_a4x(const __bf16* bc, int wm, int lrow,
                                         int quad, int swz, int qq,
                                         bf16x8 (&af)[2][2]) {
#pragma unroll
    for (int i2 = 0; i2 < 2; ++i2)
#pragma unroll
        for (int kk = 0; kk < 2; ++kk)
            af[i2][kk] = *reinterpret_cast<const bf16x8*>(
                &bc[(wm * 128 + (qq * 2 + i2) * 16 + lrow) * 64 +
                    (((kk * 4 + quad) ^ swz) << 3)]);
}

__device__ __forceinline__ void read_b6(const __bf16* bc, int wn, int lrow,
                                        int quad, int swz,
                                        bf16x8 (&bf)[3][2]) {
#pragma unroll
    for (int j = 0; j < 3; ++j)
#pragma unroll
        for (int kk = 0; kk < 2; ++kk)
            bf[j][kk] = *reinterpret_cast<const bf16x8*>(
                &bc[16384 + (wn * 48 + j * 16 + lrow) * 64 +
                    (((kk * 4 + quad) ^ swz) << 3)]);
}

__device__ __forceinline__ void mfma12(int qq, const bf16x8 (&af)[2][2],
                                       const bf16x8 (&bf)[3][2],
                                       f32x4 (&acc)[8][3]) {
    __builtin_amdgcn_s_setprio(1);
#pragma unroll
    for (int i2 = 0; i2 < 2; ++i2)
#pragma unroll
        for (int j = 0; j < 3; ++j)
#pragma unroll
            for (int kk = 0; kk < 2; ++kk)
                acc[qq * 2 + i2][j] = __builtin_amdgcn_mfma_f32_16x16x32_bf16(
                    af[i2][kk], bf[j][kk], acc[qq * 2 + i2][j], 0, 0, 0);
    __builtin_amdgcn_s_setprio(0);
}

__global__ __launch_bounds__(512, 2) void gemm1_192(
    const __bf16* __restrict__ A, const __bf16* __restrict__ Bm,
    __bf16* __restrict__ C, int M, int N, int K) {
    __shared__ __bf16 lds[2][28672];   // [buf][A 256x64 | B 192x64] 112 KB

    const int tid  = threadIdx.x;
    const int w    = tid >> 6;         // 0..7
    const int lane = tid & 63;
    const int lrow = lane & 15;
    const int quad = lane >> 4;
    const int wm   = w >> 2;           // 0..1 (M half, 128 rows)
    const int wn   = w & 3;            // 0..3 (N quarter, 48 cols)
    const int swz  = lrow & 7;

    // bijective XCD swizzle (512 % 8 == 0)
    const int chunk = (int)gridDim.x >> 3;
    const int flat  = (int)blockIdx.x;
    const int vid   = (flat & 7) * chunk + (flat >> 3);
    const int m0 = (vid & 15) * 256;   // 16 m-tiles
    const int n0 = (vid >> 4) * 192;   // 32 n-tiles

    const int lr = lane >> 3;
    const int lg = lane & 7;
    const size_t K64 = (size_t)K * 64;
    const __bf16* pA = A  + (size_t)(m0 + w * 8 + lr) * K + ((lg ^ lr) << 3);
    const __bf16* pB = Bm + (size_t)(n0 + w * 8 + lr) * K + ((lg ^ lr) << 3);

#define STA(c, tt, dst) gload_lds16(pA + (size_t)(c) * K64 + (size_t)(tt) * 64, \
                                    (dst) + (c) * 4096 + w * 512)
#define STB(c, tt, dst) gload_lds16(pB + (size_t)(c) * K64 + (size_t)(tt) * 64, \
                                    (dst) + 16384 + (c) * 4096 + w * 512)

    f32x4 acc[8][3] = {};
    bf16x8 af[2][2], bf[3][2];

    {
        __bf16* d = &lds[0][0];
        STB(0, 0, d); STB(1, 0, d); STB(2, 0, d);
        FENCE;
        STA(0, 0, d); STA(2, 0, d);
        FENCE;
        STA(1, 0, d); STA(3, 0, d);
    }
    asm volatile("s_waitcnt vmcnt(2)" ::: "memory");
    BARR;

    const int nt = K >> 6;
    for (int t = 0; t < nt - 1; ++t) {
        __bf16* bc = &lds[t & 1][0];
        __bf16* bn = &lds[(t & 1) ^ 1][0];
        const int tn = t + 1;
        read_a4x(bc, wm, lrow, quad, swz, 0, af);
        read_b6(bc, wn, lrow, quad, swz, bf);
        STB(0, tn, bn); STB(1, tn, bn);
        BARR; LGKM0;
        mfma12(0, af, bf, acc);
        BARR;
        read_a4x(bc, wm, lrow, quad, swz, 1, af);
        STB(2, tn, bn);
        BARR; LGKM0;
        mfma12(1, af, bf, acc);
        asm volatile("s_waitcnt vmcnt(3)" ::: "memory");
        BARR;
        read_a4x(bc, wm, lrow, quad, swz, 2, af);
        STA(0, tn, bn); STA(2, tn, bn);
        BARR; LGKM0;
        mfma12(2, af, bf, acc);
        BARR;
        read_a4x(bc, wm, lrow, quad, swz, 3, af);
        STA(1, tn, bn); STA(3, tn, bn);
        BARR; LGKM0;
        mfma12(3, af, bf, acc);
        asm volatile("s_waitcnt vmcnt(2)" ::: "memory");
        BARR;
    }
    {
        __bf16* bc = &lds[(nt - 1) & 1][0];
        read_a4x(bc, wm, lrow, quad, swz, 0, af);
        read_b6(bc, wn, lrow, quad, swz, bf);
        BARR; LGKM0;
        mfma12(0, af, bf, acc);
        BARR;
        read_a4x(bc, wm, lrow, quad, swz, 1, af);
        BARR; LGKM0;
        mfma12(1, af, bf, acc);
        asm volatile("s_waitcnt vmcnt(0)" ::: "memory");
        BARR;
        read_a4x(bc, wm, lrow, quad, swz, 2, af);
        BARR; LGKM0;
        mfma12(2, af, bf, acc);
        BARR;
        read_a4x(bc, wm, lrow, quad, swz, 3, af);
        BARR; LGKM0;
        mfma12(3, af, bf, acc);
    }
#undef STA
#undef STB

#pragma unroll
    for (int mf = 0; mf < 8; ++mf) {
#pragma unroll
        for (int r = 0; r < 4; ++r) {
            int row = m0 + wm * 128 + mf * 16 + quad * 4 + r;
            size_t cb = (size_t)row * N + n0 + wn * 48 + lrow;
#pragma unroll
            for (int j = 0; j < 3; ++j)
                C[cb + j * 16] = (__bf16)acc[mf][j][r];
        }
    }
}

// ---------------------------------------------------------------------------
// 128x256-tile ring-3 bf16 MFMA GEMM (NT) — R2-proven kernel, GEMM2.
// ---------------------------------------------------------------------------
__device__ __forceinline__ void stage_tile6(
    const __bf16* pA, const __bf16* pB, __bf16* buf, int w, int K) {
#pragma unroll
    for (int s = 0; s < 2; ++s)
        gload_lds16(pA + (size_t)s * 64 * K, buf + s * 4096 + w * 512);
#pragma unroll
    for (int s = 0; s < 4; ++s)
        gload_lds16(pB + (size_t)s * 64 * K, buf + 8192 + s * 4096 + w * 512);
}

template <typename OutT>
__global__ __launch_bounds__(512, 2) void gemm_bt_8ph(
    const __bf16* __restrict__ A, const __bf16* __restrict__ Bm,
    OutT* __restrict__ C, int M, int N, int K) {
    __shared__ __bf16 lds[3][24576];   // [buf][ A:128x64 | B:256x64 ] 144 KB

    const int tid  = threadIdx.x;
    const int w    = tid >> 6;         // 0..7
    const int lane = tid & 63;
    const int lrow = lane & 15;
    const int quad = lane >> 4;
    const int wm   = w >> 2;           // 0..1  (M half)
    const int wn   = w & 3;            // 0..3  (N quarter)

    const int chunk = (int)gridDim.x >> 3;
    const int flat  = (int)blockIdx.x;
    const int vid   = (flat & 7) * chunk + (flat >> 3);
    const int by    = vid & 31;        // M/128 = 32
    const int bx    = vid >> 5;
    const int m0 = by * 128;
    const int n0 = bx * 256;

    const int lr = lane >> 3;
    const int lg = lane & 7;
    const __bf16* pA = A  + (size_t)(m0 + w * 8 + lr) * K + ((lg ^ lr) << 3);
    const __bf16* pB = Bm + (size_t)(n0 + w * 8 + lr) * K + ((lg ^ lr) << 3);

    const int nt = K >> 6;             // K-tiles of 64
    f32x4 acc[4][4] = {};

    stage_tile6(pA, pB, &lds[0][0], w, K);
    stage_tile6(pA + 64, pB + 64, &lds[1][0], w, K);

    int cur = 0;
    for (int t = 0; t < nt; ++t) {
        __bf16* bufc = &lds[cur][0];
        int nxt = cur + 2; if (nxt >= 3) nxt -= 3;
        if (t + 2 < nt) {
            stage_tile6(pA + (size_t)(t + 2) * 64, pB + (size_t)(t + 2) * 64,
                        &lds[nxt][0], w, K);
            asm volatile("s_waitcnt vmcnt(12)" ::: "memory");
        } else if (t + 1 < nt) {
            asm volatile("s_waitcnt vmcnt(6)" ::: "memory");
        } else {
            asm volatile("s_waitcnt vmcnt(0)" ::: "memory");
        }
        BARR;
        FENCE;

#pragma unroll
        for (int q = 0; q < 2; ++q) {          // 2 phases x 16 MFMA per K-tile
            bf16x8 af[2][2], bfv[4][2];
#pragma unroll
            for (int i = 0; i < 2; ++i)
#pragma unroll
                for (int kk = 0; kk < 2; ++kk)
                    af[i][kk] = *reinterpret_cast<const bf16x8*>(
                        &bufc[(wm * 64 + (q * 2 + i) * 16 + lrow) * 64 +
                              (((kk * 4 + quad) ^ (lrow & 7)) << 3)]);
#pragma unroll
            for (int j = 0; j < 4; ++j)
#pragma unroll
                for (int kk = 0; kk < 2; ++kk)
                    bfv[j][kk] = *reinterpret_cast<const bf16x8*>(
                        &bufc[8192 + (wn * 64 + j * 16 + lrow) * 64 +
                              (((kk * 4 + quad) ^ (lrow & 7)) << 3)]);
            BARR;
            FENCE;
            __builtin_amdgcn_s_setprio(1);
#pragma unroll
            for (int i = 0; i < 2; ++i)
#pragma unroll
                for (int j = 0; j < 4; ++j)
#pragma unroll
                    for (int kk = 0; kk < 2; ++kk)
                        acc[q * 2 + i][j] =
                            __builtin_amdgcn_mfma_f32_16x16x32_bf16(
                                af[i][kk], bfv[j][kk], acc[q * 2 + i][j],
                                0, 0, 0);
            __builtin_amdgcn_s_setprio(0);
        }
        BARR;
        FENCE;
        cur = (cur == 2) ? 0 : cur + 1;
    }

#pragma unroll
    for (int mi = 0; mi < 4; ++mi) {
#pragma unroll
        for (int r = 0; r < 4; ++r) {
            int row = m0 + wm * 64 + mi * 16 + quad * 4 + r;
            size_t basec = (size_t)row * N + n0 + wn * 64 + lrow;
#pragma unroll
            for (int nj = 0; nj < 4; ++nj)
                C[basec + nj * 16] = (OutT)acc[mi][nj][r];
        }
    }
}

// ---------------------------------------------------------------------------
// RMSNorm (flat 2048) + RoPE in place on bf16 q or k.  (unchanged)
// ---------------------------------------------------------------------------
__global__ __launch_bounds__(256) void normrope_kernel(
    __bf16* __restrict__ qkv, const float* __restrict__ qw,
    const float* __restrict__ kw) {
    const int row = blockIdx.x;
    const int sel = blockIdx.y;
    const int pos = row & (S_ - 1);
    __bf16* p = qkv + (size_t)row * QKV_ + sel * 2048;
    const float* w = sel ? kw : qw;

    __shared__ float buf[2048];
    __shared__ float red[4];
    const int tid = threadIdx.x;
    const int e   = tid * 8;

    bf16x8 t = *reinterpret_cast<const bf16x8*>(&p[e]);
    float xs[8];
    float ss = 0.f;
#pragma unroll
    for (int u = 0; u < 8; ++u) {
        xs[u] = (float)t[u];
        buf[e + u] = xs[u];
        ss += xs[u] * xs[u];
    }
#pragma unroll
    for (int off = 32; off > 0; off >>= 1) ss += __shfl_xor(ss, off, 64);
    if ((tid & 63) == 0) red[tid >> 6] = ss;
    __syncthreads();
    float total = red[0] + red[1] + red[2] + red[3];
    float scale = rsqrtf(total * (1.f / 2048.f) + EPS_);

    const float kfreq2 = -0.20762050593046f;  // -log2(10000)/64
    const int jbase = e & 63;
    const bool first = (e & 127) < 64;
    const int ep = e ^ 64;

    float ps[8], ws[8], pw[8];
#pragma unroll
    for (int u = 0; u < 8; ++u) ps[u] = buf[ep + u];
    float4 w0 = *reinterpret_cast<const float4*>(&w[e]);
    float4 w1 = *reinterpret_cast<const float4*>(&w[e + 4]);
    float4 p0 = *reinterpret_cast<const float4*>(&w[ep]);
    float4 p1 = *reinterpret_cast<const float4*>(&w[ep + 4]);
    ws[0]=w0.x; ws[1]=w0.y; ws[2]=w0.z; ws[3]=w0.w;
    ws[4]=w1.x; ws[5]=w1.y; ws[6]=w1.z; ws[7]=w1.w;
    pw[0]=p0.x; pw[1]=p0.y; pw[2]=p0.z; pw[3]=p0.w;
    pw[4]=p1.x; pw[5]=p1.y; pw[6]=p1.z; pw[7]=p1.w;

    bf16x8 o8;
#pragma unroll
    for (int u = 0; u < 8; ++u) {
        float inv_freq = exp2f((float)(jbase + u) * kfreq2);
        float ang = (float)pos * inv_freq;
        float sn = __sinf(ang);
        float cs = __cosf(ang);
        float a  = xs[u] * scale * ws[u];
        float bb = ps[u] * scale * pw[u];
        float o  = first ? (a * cs - bb * sn) : (a * cs + bb * sn);
        o8[u] = (__bf16)o;
    }
    *reinterpret_cast<bf16x8*>(&p[e]) = o8;
}

// ---------------------------------------------------------------------------
// MFMA flash attention — R7: EXACT R5 structure (512 blocks, heavy-first,
// 128-row Q-tile, 8 waves, prefetch-1 ping-pong, launch_bounds(512,4))
// plus ONLY the R6-verified K-swizzle (conflicts 4.26M -> 0):
//   staging: global col granule pre-swizzled (lane&3)^((lane>>3)&3)
//   read:    granule quad^((lrow>>1)&3)  (same key for rows lrow, 16+lrow)
// R6's paired-tile structure REVERTED (111.7 -> 206 us: serializing two
// dep-chains in one lockstep block killed cross-block latency hiding).
// ---------------------------------------------------------------------------
#define VTP 36   // Vt/Pb row stride in bf16: 72B rows, 2-way-max aliasing

__global__ __launch_bounds__(512, 4) void attn_mfma(
    const __bf16* __restrict__ qkv, __bf16* __restrict__ aout) {
    const int flat = (int)blockIdx.x;
    const int vid  = (flat & 7) * 64 + (flat >> 3);
    const int bh   = vid >> 4;
    const int qt   = 15 - (vid & 15);     // heavy diagonal tiles first
    const int b    = bh >> 4;
    const int h    = bh & (NH_ - 1);
    const int q0   = qt * 128;
    const int tid  = threadIdx.x;
    const int w    = tid >> 6;            // 0..7
    const int lane = tid & 63;
    const int lrow = lane & 15;
    const int quad = lane >> 4;

    __shared__ __bf16 Ks[2][4][32 * 32];   // [buf][kc][key*32+c]  16 KB
    __shared__ __bf16 Vt[2][128 * VTP];    // [buf][d*VTP+key]     18 KB
    __shared__ __bf16 Pb[8][16 * VTP];     // [wave][q*VTP+key]     9 KB

    const size_t base = (size_t)(b * S_) * QKV_ + (size_t)h * HD_;
    const int qrow = q0 + w * 16 + lrow;   // this lane's q-row (B-frag n)

    bf16x8 qf[4];
#pragma unroll
    for (int kc = 0; kc < 4; ++kc)
        qf[kc] = *reinterpret_cast<const bf16x8*>(
            &qkv[base + (size_t)qrow * QKV_ + kc * 32 + quad * 8]);

    f32x4 o[8] = {};          // O^T: d = dt*16+quad*4+r, q = lrow
    float lpart = 0.f;        // per-lane partial sum of p

    const int ktmax_w   = 4 * qt + (w >> 1);  // wave's diagonal tile
    const int ktmax_blk = 4 * qt + 3;
    const float sl2 = 0.12751743671f;   // (1/sqrt(128))*log2(e)
    const int kgq = (quad ^ ((lrow >> 1) & 3)) * 8;  // swizzled K granule

    // K staging: wave w stages chunk (w>>1), key-half (w&1); global granule
    // pre-swizzled so the linear-dest DMA lands swizzled data (rule 21).
    const __bf16* kg0 = qkv + base + 2048 +
                        (size_t)((w & 1) * 16 + (lane >> 2)) * QKV_ +
                        (w >> 1) * 32 + (((lane & 3) ^ ((lane >> 3) & 3)) << 3);
    const int g  = tid >> 4;
    const int kp = tid & 15;
    const __bf16* vg0 = qkv + base + 4096 + (size_t)(kp * 2) * QKV_ + g * 8;

    gload_lds16(kg0, &Ks[0][w >> 1][(w & 1) * 512]);
    bf16x8 v0 = {}, v1 = {};
    if (tid < 256) {
        v0 = *reinterpret_cast<const bf16x8*>(vg0);
        v1 = *reinterpret_cast<const bf16x8*>(vg0 + QKV_);
    }

    for (int kt = 0; kt <= ktmax_blk; ++kt) {
        const int buf = kt & 1;
        if (tid < 256) {
#pragma unroll
            for (int u = 0; u < 8; ++u) {
                bf16x2 pr = {v0[u], v1[u]};
                *reinterpret_cast<bf16x2*>(
                    &Vt[buf][(g * 8 + u) * VTP + kp * 2]) = pr;
            }
        }
        __syncthreads();
        if (kt < ktmax_blk) {
            const __bf16* kg = kg0 + (size_t)(kt + 1) * 32 * QKV_;
            gload_lds16(kg, &Ks[buf ^ 1][w >> 1][(w & 1) * 512]);
            if (tid < 256) {
                const __bf16* vg = vg0 + (size_t)(kt + 1) * 32 * QKV_;
                v0 = *reinterpret_cast<const bf16x8*>(vg);
                v1 = *reinterpret_cast<const bf16x8*>(vg + QKV_);
            }
        }
        if (kt <= ktmax_w) {   // wave-uniform causal skip
            f32x4 sc[2] = {};
            __builtin_amdgcn_s_setprio(1);
#pragma unroll
            for (int kc = 0; kc < 4; ++kc) {
                bf16x8 kf0 = *reinterpret_cast<const bf16x8*>(
                    &Ks[buf][kc][lrow * 32 + kgq]);
                bf16x8 kf1 = *reinterpret_cast<const bf16x8*>(
                    &Ks[buf][kc][(16 + lrow) * 32 + kgq]);
                sc[0] = __builtin_amdgcn_mfma_f32_16x16x32_bf16(
                    kf0, qf[kc], sc[0], 0, 0, 0);
                sc[1] = __builtin_amdgcn_mfma_f32_16x16x32_bf16(
                    kf1, qf[kc], sc[1], 0, 0, 0);
            }
            __builtin_amdgcn_s_setprio(0);
            const bool diag = (kt == ktmax_w);
            float p[2][4];
#pragma unroll
            for (int m2 = 0; m2 < 2; ++m2)
#pragma unroll
                for (int r = 0; r < 4; ++r) {
                    float s = sc[m2][r] * sl2 - 32.f;
                    if (diag && kt * 32 + m2 * 16 + quad * 4 + r > qrow)
                        s = -1e30f;
                    p[m2][r] = exp2f(s);
                    lpart += p[m2][r];
                }
#pragma unroll
            for (int m2 = 0; m2 < 2; ++m2) {
                bf16x4 pb = {(__bf16)p[m2][0], (__bf16)p[m2][1],
                             (__bf16)p[m2][2], (__bf16)p[m2][3]};
                *reinterpret_cast<bf16x4*>(
                    &Pb[w][lrow * VTP + m2 * 16 + quad * 4]) = pb;
            }
            bf16x8 pf = *reinterpret_cast<const bf16x8*>(
                &Pb[w][lrow * VTP + quad * 8]);
            __builtin_amdgcn_s_setprio(1);
#pragma unroll
            for (int dt = 0; dt < 8; ++dt) {
                bf16x8 vf = *reinterpret_cast<const bf16x8*>(
                    &Vt[buf][(dt * 16 + lrow) * VTP + quad * 8]);
                o[dt] = __builtin_amdgcn_mfma_f32_16x16x32_bf16(
                    vf, pf, o[dt], 0, 0, 0);
            }
            __builtin_amdgcn_s_setprio(0);
        }
    }

    lpart += __shfl_xor(lpart, 16, 64);
    lpart += __shfl_xor(lpart, 32, 64);
    const float invl = 1.f / lpart;
    const size_t orow = (size_t)(b * S_ + qrow) * (NH_ * HD_) + (size_t)h * HD_;
#pragma unroll
    for (int dt = 0; dt < 8; ++dt) {
        bf16x4 ov = {(__bf16)(o[dt][0] * invl), (__bf16)(o[dt][1] * invl),
                     (__bf16)(o[dt][2] * invl), (__bf16)(o[dt][3] * invl)};
        *reinterpret_cast<bf16x4*>(&aout[orow + dt * 16 + quad * 4]) = ov;
    }
}

// ---------------------------------------------------------------------------
extern "C" void kernel_launch(void* const* d_in, const int* in_sizes, int n_in,
                              void* d_out, int out_size, void* d_ws,
                              size_t ws_size, hipStream_t stream) {
    const float* x     = (const float*)d_in[0];
    const float* w_in  = (const float*)d_in[1];
    const float* w_out = (const float*)d_in[2];
    const float* qw    = (const float*)d_in[3];
    const float* kw    = (const float*)d_in[4];
    float* out = (float*)d_out;

    const int M = B_ * S_;  // 4096
    // workspace (bytes), peak 96 MiB:
    //   [0,48M) qkv_bf16 | [48M,56M) w_out_bf16 | [56M,72M) x_bf16/attn_bf16
    //   [72M,96M) w_in_bf16
    char* ws = (char*)d_ws;
    __bf16* qkv_b   = (__bf16*)(ws);
    __bf16* w_out_b = (__bf16*)(ws + (size_t)50331648);
    __bf16* x_b     = (__bf16*)(ws + (size_t)58720256);
    __bf16* attn_b  = x_b;  // x_bf16 dead after GEMM1
    __bf16* w_in_b  = (__bf16*)(ws + (size_t)75497472);

    dim3 blk(256);

    // single fused cast launch: x, w_in, w_out
    {
        const int na4 = (M * HID_) / 4;          // 2,097,152
        const int nb4 = (QKV_ * HID_) / 4;       // 3,145,728
        const int nc4 = (HID_ * NH_ * HD_) / 4;  // 1,048,576
        const int tot = na4 + nb4 + nc4;
        cast3_f32_bf16<<<dim3((tot + 255) / 256), blk, 0, stream>>>(
            x, x_b, na4, w_in, w_in_b, nb4, w_out, w_out_b, nc4);
    }

    // qkv = x @ w_in^T   (4096 x 6144 x 2048): 16x32 = 512 blocks = 2 rounds
    gemm1_192<<<dim3((M / 256) * (QKV_ / 192)), dim3(512), 0, stream>>>(
        x_b, w_in_b, qkv_b, M, QKV_, HID_);
    // rmsnorm + rope on q and k, in place
    normrope_kernel<<<dim3(M, 2), blk, 0, stream>>>(qkv_b, qw, kw);
    // causal MFMA flash attention: 128-row Q-tiles, 8 waves, XCD-swizzled
    attn_mfma<<<dim3((S_ / 128) * B_ * NH_), dim3(512), 0, stream>>>(
        qkv_b, attn_b);
    // out = attn @ w_out^T  (4096 x 2048 x 2048): 32x8 = 256 blocks = 1 round
    gemm_bt_8ph<float><<<dim3((M / 128) * (HID_ / 256)), dim3(512), 0,
                         stream>>>(attn_b, w_out_b, out, M, HID_, NH_ * HD_);
}